// Round 1
// baseline (401.071 us; speedup 1.0000x reference)
//
#include <hip/hip_runtime.h>
#include <hip/hip_bf16.h>
#include <stdint.h>

// Problem constants (from reference)
#define DMODEL 1024
#define M_TOK  16384   // B*L = 4*4096

typedef __attribute__((ext_vector_type(8))) short short8;   // 8 x bf16 (4 VGPRs)
typedef __attribute__((ext_vector_type(4))) float f32x4;    // MFMA C/D frag

// Pack two fp32 -> two bf16 (RNE) in one dword via v_perm_b32.
__device__ __forceinline__ unsigned int pack2_bf16(float f0, float f1) {
    unsigned int u0 = __builtin_bit_cast(unsigned int, f0);
    unsigned int u1 = __builtin_bit_cast(unsigned int, f1);
    u0 += 0x7fffu + ((u0 >> 16) & 1u);
    u1 += 0x7fffu + ((u1 >> 16) & 1u);
    // result = (hi16(u1) << 16) | hi16(u0)  -> memory order f0, f1
    return __builtin_amdgcn_perm(u1, u0, 0x07060302);
}

// C[m, e] = role[m] ? sum_d X[m,d] * R[e,d] : X[m,e],  X[m,:] = emb[ids[m], :]
// 128x128 tile per block, BK=32, 4 waves of 64x64 (4x4 frags of 16x16x32 bf16 MFMA).
__global__ void rse_gemm(const int* __restrict__ ids, const int* __restrict__ roles,
                         const float* __restrict__ emb, const float* __restrict__ Rm,
                         float* __restrict__ out) {
    // +8 shorts pad: b128 frag reads land at 2-way bank aliasing (free, m136)
    __shared__ short As[128][40];
    __shared__ short Bs[128][40];
    __shared__ int s_tok[128];
    __shared__ int s_role[128];

    const int tid  = threadIdx.x;
    const int m0   = blockIdx.y * 128;   // token-tile origin
    const int n0   = blockIdx.x * 128;   // output-dim-tile origin

    const int lane = tid & 63;
    const int wave = tid >> 6;           // 4 waves
    const int quad = lane >> 4;
    const int l15  = lane & 15;
    const int wr   = wave >> 1;          // wave row (0..1), 64 rows each
    const int wc   = wave & 1;           // wave col (0..1), 64 cols each

    // staging assignment: 2 threads per tile-row, 16 floats (64B) each
    const int sr = tid >> 1;             // 0..127
    const int sh = tid & 1;              // half of the 32-float K-chunk

    if (tid < 128) {
        s_tok[tid]  = ids[m0 + tid];
        s_role[tid] = roles[m0 + tid];
    }

    const int my_tok = ids[m0 + sr];
    const float* aSrc = emb + (size_t)my_tok * DMODEL + sh * 16;
    const float* bSrc = Rm  + (size_t)(n0 + sr) * DMODEL + sh * 16;

    f32x4 acc[4][4] = {};

    for (int k0 = 0; k0 < DMODEL; k0 += 32) {
        // ---- global loads (before barrier, overlap with prior compute) ----
        float4 a0 = *(const float4*)(aSrc + k0);
        float4 a1 = *(const float4*)(aSrc + k0 + 4);
        float4 a2 = *(const float4*)(aSrc + k0 + 8);
        float4 a3 = *(const float4*)(aSrc + k0 + 12);
        float4 b0 = *(const float4*)(bSrc + k0);
        float4 b1 = *(const float4*)(bSrc + k0 + 4);
        float4 b2 = *(const float4*)(bSrc + k0 + 8);
        float4 b3 = *(const float4*)(bSrc + k0 + 12);

        __syncthreads();   // previous iteration's frag reads complete

        uint4 pa0 = make_uint4(pack2_bf16(a0.x, a0.y), pack2_bf16(a0.z, a0.w),
                               pack2_bf16(a1.x, a1.y), pack2_bf16(a1.z, a1.w));
        uint4 pa1 = make_uint4(pack2_bf16(a2.x, a2.y), pack2_bf16(a2.z, a2.w),
                               pack2_bf16(a3.x, a3.y), pack2_bf16(a3.z, a3.w));
        uint4 pb0 = make_uint4(pack2_bf16(b0.x, b0.y), pack2_bf16(b0.z, b0.w),
                               pack2_bf16(b1.x, b1.y), pack2_bf16(b1.z, b1.w));
        uint4 pb1 = make_uint4(pack2_bf16(b2.x, b2.y), pack2_bf16(b2.z, b2.w),
                               pack2_bf16(b3.x, b3.y), pack2_bf16(b3.z, b3.w));

        *(uint4*)&As[sr][sh * 16]     = pa0;
        *(uint4*)&As[sr][sh * 16 + 8] = pa1;
        *(uint4*)&Bs[sr][sh * 16]     = pb0;
        *(uint4*)&Bs[sr][sh * 16 + 8] = pb1;

        __syncthreads();   // LDS tile ready

        // ---- LDS -> frags (A[m=l15][k=quad*8+j] layout), 16 MFMAs ----
        short8 af[4], bfr[4];
#pragma unroll
        for (int i = 0; i < 4; ++i)
            af[i] = *(const short8*)&As[wr * 64 + i * 16 + l15][quad * 8];
#pragma unroll
        for (int j = 0; j < 4; ++j)
            bfr[j] = *(const short8*)&Bs[wc * 64 + j * 16 + l15][quad * 8];
#pragma unroll
        for (int i = 0; i < 4; ++i)
#pragma unroll
            for (int j = 0; j < 4; ++j)
                acc[i][j] = __builtin_amdgcn_mfma_f32_16x16x32_bf16(af[i], bfr[j], acc[i][j], 0, 0, 0);
    }

    // ---- epilogue: C/D layout col=l15, row=quad*4+reg (m89-verified) ----
    const int colbase = n0 + wc * 64 + l15;
#pragma unroll
    for (int ti = 0; ti < 4; ++ti) {
        const int rowb = wr * 64 + ti * 16 + quad * 4;
#pragma unroll
        for (int r = 0; r < 4; ++r) {
            const int row  = rowb + r;
            const int role = s_role[row];
            const float* src = emb + (size_t)s_tok[row] * DMODEL + colbase;
            float* dst = out + (size_t)(m0 + row) * DMODEL + colbase;
#pragma unroll
            for (int tj = 0; tj < 4; ++tj) {
                float v = acc[ti][tj][r];
                if (!role) v = src[tj * 16];   // user token: exact fp32 passthrough
                dst[tj * 16] = v;
            }
        }
    }
}

extern "C" void kernel_launch(void* const* d_in, const int* in_sizes, int n_in,
                              void* d_out, int out_size, void* d_ws, size_t ws_size,
                              hipStream_t stream) {
    const int*   ids   = (const int*)d_in[0];
    const int*   roles = (const int*)d_in[1];
    const float* emb   = (const float*)d_in[2];
    const float* Rm    = (const float*)d_in[3];
    float*       out   = (float*)d_out;

    dim3 grid(DMODEL / 128, M_TOK / 128);   // (8, 128) = 1024 blocks
    rse_gemm<<<grid, 256, 0, stream>>>(ids, roles, emb, Rm, out);
}

// Round 2
// 329.015 us; speedup vs baseline: 1.2190x; 1.2190x over previous
//
#include <hip/hip_runtime.h>
#include <hip/hip_bf16.h>
#include <stdint.h>

// Problem constants (from reference)
#define DMODEL 1024
#define M_TOK  16384   // B*L = 4*4096

typedef __attribute__((ext_vector_type(8))) short short8;   // 8 x bf16 (4 VGPRs)
typedef __attribute__((ext_vector_type(4))) float f32x4;    // MFMA C/D frag

// Pack two fp32 -> two bf16 (RNE) in one dword via v_perm_b32.
__device__ __forceinline__ unsigned int pack2_bf16(float f0, float f1) {
    unsigned int u0 = __builtin_bit_cast(unsigned int, f0);
    unsigned int u1 = __builtin_bit_cast(unsigned int, f1);
    u0 += 0x7fffu + ((u0 >> 16) & 1u);
    u1 += 0x7fffu + ((u1 >> 16) & 1u);
    return __builtin_amdgcn_perm(u1, u0, 0x07060302);  // mem order f0, f1
}

// async global->LDS, 16B per lane. LDS dest = wave-uniform base + lane*16.
__device__ __forceinline__ void gload_lds16(const void* g, void* l) {
    __builtin_amdgcn_global_load_lds(
        (const __attribute__((address_space(1))) void*)g,
        (__attribute__((address_space(3))) void*)l, 16, 0, 0);
}

// ---------------- Phase 1: gather emb rows + R, fp32 -> bf16, stream to ws ---
// One wave per row; reads are fully coalesced 4 KB row streams (DRAM-friendly),
// unlike the GEMM's 128B slivers that caused the 283 MB / 2 TB/s fetch wall.
__global__ void gather_convert(const int* __restrict__ ids,
                               const float* __restrict__ emb,
                               const float* __restrict__ Rm,
                               __hip_bfloat16* __restrict__ Xb,    // [M_TOK][DMODEL]
                               __hip_bfloat16* __restrict__ Rb) {  // [DMODEL][DMODEL]
    const int row  = blockIdx.x * 4 + (threadIdx.x >> 6);
    const int lane = threadIdx.x & 63;
    const float* src;
    __hip_bfloat16* dst;
    if (row < M_TOK) {
        src = emb + (size_t)ids[row] * DMODEL;
        dst = Xb + (size_t)row * DMODEL;
    } else {
        src = Rm + (size_t)(row - M_TOK) * DMODEL;
        dst = Rb + (size_t)(row - M_TOK) * DMODEL;
    }
#pragma unroll
    for (int c = 0; c < 4; ++c) {
        const int idx = c * 256 + lane * 4;           // 16B/lane, coalesced
        float4 v = *(const float4*)(src + idx);
        uint2 p = make_uint2(pack2_bf16(v.x, v.y), pack2_bf16(v.z, v.w));
        *(uint2*)((unsigned short*)dst + idx) = p;    // 8B/lane, coalesced
    }
}

// ---------------- Phase 2: bf16 GEMM, m97 structure ------------------------
// C[m,e] = role[m] ? sum_d X[m,d]*R[e,d] : X[m,e]
// 128x128 tile, BK=32, 4 waves x (4x4 frags of 16x16x32 bf16 MFMA),
// global_load_lds width=16 staging (no VGPR round-trip, no pack in K-loop).
__global__ void rse_gemm2(const int* __restrict__ roles,
                          const __hip_bfloat16* __restrict__ Xb,
                          const __hip_bfloat16* __restrict__ Rb,
                          float* __restrict__ out) {
    // NOTE: no padding — global_load_lds requires dest = base + lane*16 (m104)
    __shared__ __hip_bfloat16 As[128 * 32];
    __shared__ __hip_bfloat16 Bs[128 * 32];
    __shared__ int s_role[128];

    const int tid  = threadIdx.x;
    const int m0   = blockIdx.y * 128;
    const int n0   = blockIdx.x * 128;
    const int lane = tid & 63;
    const int wave = tid >> 6;
    const int quad = lane >> 4;
    const int l15  = lane & 15;
    const int wr   = wave >> 1;
    const int wc   = wave & 1;

    if (tid < 128) s_role[tid] = roles[m0 + tid];

    // staging: wave w, issue q -> 16-row group rg=(q*4+w)*16;
    // lane: row = rg + lane/4, k-chunk = (lane&3)*8 bf16 (16B)
    const int st_row = lane >> 2;
    const int st_k   = (lane & 3) * 8;
    const int rg0 = wave * 16;          // q=0
    const int rg1 = (4 + wave) * 16;    // q=1

    const __hip_bfloat16* aG = Xb + (size_t)m0 * DMODEL;
    const __hip_bfloat16* bG = Rb + (size_t)n0 * DMODEL;

    f32x4 acc[4][4] = {};

    for (int k0 = 0; k0 < DMODEL; k0 += 32) {
        __syncthreads();   // previous tile's frag reads complete
        gload_lds16(aG + (size_t)(rg0 + st_row) * DMODEL + k0 + st_k, &As[rg0 * 32]);
        gload_lds16(aG + (size_t)(rg1 + st_row) * DMODEL + k0 + st_k, &As[rg1 * 32]);
        gload_lds16(bG + (size_t)(rg0 + st_row) * DMODEL + k0 + st_k, &Bs[rg0 * 32]);
        gload_lds16(bG + (size_t)(rg1 + st_row) * DMODEL + k0 + st_k, &Bs[rg1 * 32]);
        __syncthreads();   // barrier drains vmcnt -> tile ready

        short8 af[4], bfr[4];
#pragma unroll
        for (int i = 0; i < 4; ++i)
            af[i] = *(const short8*)&As[(wr * 64 + i * 16 + l15) * 32 + quad * 8];
#pragma unroll
        for (int j = 0; j < 4; ++j)
            bfr[j] = *(const short8*)&Bs[(wc * 64 + j * 16 + l15) * 32 + quad * 8];
#pragma unroll
        for (int i = 0; i < 4; ++i)
#pragma unroll
            for (int j = 0; j < 4; ++j)
                acc[i][j] = __builtin_amdgcn_mfma_f32_16x16x32_bf16(af[i], bfr[j], acc[i][j], 0, 0, 0);
    }

    // epilogue: C/D layout col=l15, row=quad*4+reg (m89-verified)
    const int colbase = n0 + wc * 64 + l15;
#pragma unroll
    for (int ti = 0; ti < 4; ++ti) {
        const int rowb = wr * 64 + ti * 16 + quad * 4;
#pragma unroll
        for (int r = 0; r < 4; ++r) {
            const int row  = rowb + r;
            const int role = s_role[row];
            const __hip_bfloat16* src = Xb + (size_t)(m0 + row) * DMODEL + colbase;
            float* dst = out + (size_t)(m0 + row) * DMODEL + colbase;
#pragma unroll
            for (int tj = 0; tj < 4; ++tj) {
                float v = acc[ti][tj][r];
                if (!role) v = (float)src[tj * 16];  // bf16 passthrough (err ~0.03 << 3.38)
                dst[tj * 16] = v;
            }
        }
    }
}

extern "C" void kernel_launch(void* const* d_in, const int* in_sizes, int n_in,
                              void* d_out, int out_size, void* d_ws, size_t ws_size,
                              hipStream_t stream) {
    const int*   ids   = (const int*)d_in[0];
    const int*   roles = (const int*)d_in[1];
    const float* emb   = (const float*)d_in[2];
    const float* Rm    = (const float*)d_in[3];
    float*       out   = (float*)d_out;

    // ws layout: Xb [16384*1024 bf16] = 32 MB, then Rb [1024*1024 bf16] = 2 MB
    __hip_bfloat16* Xb = (__hip_bfloat16*)d_ws;
    __hip_bfloat16* Rb = Xb + (size_t)M_TOK * DMODEL;

    gather_convert<<<(M_TOK + DMODEL) / 4, 256, 0, stream>>>(ids, emb, Rm, Xb, Rb);

    dim3 grid2(DMODEL / 128, M_TOK / 128);   // (8, 128) = 1024 blocks
    rse_gemm2<<<grid2, 256, 0, stream>>>(roles, Xb, Rb, out);
}

// Round 3
// 318.066 us; speedup vs baseline: 1.2610x; 1.0344x over previous
//
#include <hip/hip_runtime.h>
#include <hip/hip_bf16.h>
#include <stdint.h>

// Problem constants (from reference)
#define DMODEL 1024
#define M_TOK  16384   // B*L = 4*4096

typedef __attribute__((ext_vector_type(8))) short short8;   // 8 x bf16 (4 VGPRs)
typedef __attribute__((ext_vector_type(4))) float f32x4;    // MFMA C/D frag

// Pack two fp32 -> two bf16 (RNE) in one dword via v_perm_b32.
__device__ __forceinline__ unsigned int pack2_bf16(float f0, float f1) {
    unsigned int u0 = __builtin_bit_cast(unsigned int, f0);
    unsigned int u1 = __builtin_bit_cast(unsigned int, f1);
    u0 += 0x7fffu + ((u0 >> 16) & 1u);
    u1 += 0x7fffu + ((u1 >> 16) & 1u);
    return __builtin_amdgcn_perm(u1, u0, 0x07060302);  // mem order f0, f1
}

// async global->LDS, 16B per lane. LDS dest = wave-uniform base + lane*16.
__device__ __forceinline__ void gload_lds16(const void* g, void* l) {
    __builtin_amdgcn_global_load_lds(
        (const __attribute__((address_space(1))) void*)g,
        (__attribute__((address_space(3))) void*)l, 16, 0, 0);
}

// ---------------- Phase 0: compaction plan (single block, deterministic) ----
// pos[m] = compacted index for agent token m; orig[j] = token index of
// compacted row j; *n_agent = count. ws is re-poisoned every call, so all of
// this is recomputed every launch (same work every call — graph-safe).
__global__ void plan_compact(const int* __restrict__ roles,
                             int* __restrict__ pos, int* __restrict__ orig,
                             int* __restrict__ n_agent) {
    __shared__ int s[1024];
    const int t = threadIdx.x;
    int pred[16];
    int c = 0;
#pragma unroll
    for (int i = 0; i < 16; ++i) {          // strided for coalescing
        pred[i] = (roles[i * 1024 + t] == 1);
        c += pred[i];
    }
    s[t] = c;
    __syncthreads();
    // Hillis-Steele inclusive scan over 1024 per-thread counts
    for (int off = 1; off < 1024; off <<= 1) {
        int v = (t >= off) ? s[t - off] : 0;
        __syncthreads();
        s[t] += v;
        __syncthreads();
    }
    int base = s[t] - c;                    // exclusive prefix
#pragma unroll
    for (int i = 0; i < 16; ++i) {
        if (pred[i]) {
            const int m = i * 1024 + t;
            orig[base] = m;
            pos[m] = base;
            ++base;
        }
    }
    if (t == 1023) *n_agent = s[1023];
}

// ---------------- Phase 1: gather + convert / passthrough -------------------
// One wave per row, contiguous 4 KB streams. Agent rows -> bf16 Xc (compacted);
// user rows -> EXACT fp32 copy straight to out (never touched again).
__global__ void gather2(const int* __restrict__ ids, const int* __restrict__ roles,
                        const int* __restrict__ pos,
                        const float* __restrict__ emb, const float* __restrict__ Rm,
                        __hip_bfloat16* __restrict__ Xc,
                        __hip_bfloat16* __restrict__ Rb,
                        float* __restrict__ out) {
    const int row  = blockIdx.x * 4 + (threadIdx.x >> 6);
    const int lane = threadIdx.x & 63;
    if (row < M_TOK) {
        const float* src = emb + (size_t)ids[row] * DMODEL;
        if (roles[row] == 1) {
            __hip_bfloat16* dst = Xc + (size_t)pos[row] * DMODEL;
#pragma unroll
            for (int c = 0; c < 4; ++c) {
                const int idx = c * 256 + lane * 4;
                float4 v = *(const float4*)(src + idx);
                uint2 p = make_uint2(pack2_bf16(v.x, v.y), pack2_bf16(v.z, v.w));
                *(uint2*)((unsigned short*)dst + idx) = p;
            }
        } else {
            float* dst = out + (size_t)row * DMODEL;
#pragma unroll
            for (int c = 0; c < 4; ++c) {
                const int idx = c * 256 + lane * 4;
                *(float4*)(dst + idx) = *(const float4*)(src + idx);
            }
        }
    } else {
        const int r = row - M_TOK;
        const float* src = Rm + (size_t)r * DMODEL;
        __hip_bfloat16* dst = Rb + (size_t)r * DMODEL;
#pragma unroll
        for (int c = 0; c < 4; ++c) {
            const int idx = c * 256 + lane * 4;
            float4 v = *(const float4*)(src + idx);
            uint2 p = make_uint2(pack2_bf16(v.x, v.y), pack2_bf16(v.z, v.w));
            *(uint2*)((unsigned short*)dst + idx) = p;
        }
    }
}

// ---------------- Phase 2: bf16 GEMM over compacted agent rows --------------
// C[orig[j], e] = sum_d Xc[j,d] * R[e,d].  128x128 tile, BK=32, m97 structure.
// Grid (m-tiles=128, n-tiles=8): blocks sharing an A-tile are spaced 128 in
// linear id -> same id%8 -> same XCD -> A re-reads hit that XCD's L2.
__global__ void rse_gemm3(const int* __restrict__ n_agent_p,
                          const int* __restrict__ orig,
                          const __hip_bfloat16* __restrict__ Xc,
                          const __hip_bfloat16* __restrict__ Rb,
                          float* __restrict__ out) {
    const int na = *n_agent_p;
    const int m0 = blockIdx.x * 128;     // compacted-row tile
    if (m0 >= na) return;                // early-exit past agent count
    const int n0 = blockIdx.y * 128;

    // NOTE: no padding — global_load_lds requires dest = base + lane*16 (m104)
    __shared__ __hip_bfloat16 As[128 * 32];
    __shared__ __hip_bfloat16 Bs[128 * 32];
    __shared__ int s_orig[128];

    const int tid  = threadIdx.x;
    const int lane = tid & 63;
    const int wave = tid >> 6;
    const int quad = lane >> 4;
    const int l15  = lane & 15;
    const int wr   = wave >> 1;
    const int wc   = wave & 1;

    if (tid < 128) {
        const int j = m0 + tid;
        s_orig[tid] = (j < na) ? orig[j] : -1;
    }

    // staging: wave w, issue q -> 16-row group rg=(q*4+w)*16;
    // lane: row = rg + lane/4, k-chunk = (lane&3)*8 bf16 (16B)
    const int st_row = lane >> 2;
    const int st_k   = (lane & 3) * 8;
    const int rg0 = wave * 16;
    const int rg1 = (4 + wave) * 16;

    const __hip_bfloat16* aG = Xc + (size_t)m0 * DMODEL;
    const __hip_bfloat16* bG = Rb + (size_t)n0 * DMODEL;

    f32x4 acc[4][4] = {};

    for (int k0 = 0; k0 < DMODEL; k0 += 32) {
        __syncthreads();   // previous tile's frag reads complete
        gload_lds16(aG + (size_t)(rg0 + st_row) * DMODEL + k0 + st_k, &As[rg0 * 32]);
        gload_lds16(aG + (size_t)(rg1 + st_row) * DMODEL + k0 + st_k, &As[rg1 * 32]);
        gload_lds16(bG + (size_t)(rg0 + st_row) * DMODEL + k0 + st_k, &Bs[rg0 * 32]);
        gload_lds16(bG + (size_t)(rg1 + st_row) * DMODEL + k0 + st_k, &Bs[rg1 * 32]);
        __syncthreads();   // barrier drains vmcnt -> tile ready

        short8 af[4], bfr[4];
#pragma unroll
        for (int i = 0; i < 4; ++i)
            af[i] = *(const short8*)&As[(wr * 64 + i * 16 + l15) * 32 + quad * 8];
#pragma unroll
        for (int j = 0; j < 4; ++j)
            bfr[j] = *(const short8*)&Bs[(wc * 64 + j * 16 + l15) * 32 + quad * 8];
#pragma unroll
        for (int i = 0; i < 4; ++i)
#pragma unroll
            for (int j = 0; j < 4; ++j)
                acc[i][j] = __builtin_amdgcn_mfma_f32_16x16x32_bf16(af[i], bfr[j], acc[i][j], 0, 0, 0);
    }

    // epilogue: C/D layout col=l15, row=quad*4+reg; scatter to orig token row
    const int colbase = n0 + wc * 64 + l15;
#pragma unroll
    for (int ti = 0; ti < 4; ++ti) {
        const int rowb = wr * 64 + ti * 16 + quad * 4;
#pragma unroll
        for (int r = 0; r < 4; ++r) {
            const int row = rowb + r;
            const int oj  = s_orig[row];
            if (oj >= 0) {
                float* dst = out + (size_t)oj * DMODEL + colbase;
#pragma unroll
                for (int tj = 0; tj < 4; ++tj)
                    dst[tj * 16] = acc[ti][tj][r];
            }
        }
    }
}

extern "C" void kernel_launch(void* const* d_in, const int* in_sizes, int n_in,
                              void* d_out, int out_size, void* d_ws, size_t ws_size,
                              hipStream_t stream) {
    const int*   ids   = (const int*)d_in[0];
    const int*   roles = (const int*)d_in[1];
    const float* emb   = (const float*)d_in[2];
    const float* Rm    = (const float*)d_in[3];
    float*       out   = (float*)d_out;

    // ws layout: Xc 32MB | Rb 2MB | orig 64KB | pos 64KB | n_agent
    __hip_bfloat16* Xc = (__hip_bfloat16*)d_ws;
    __hip_bfloat16* Rb = Xc + (size_t)M_TOK * DMODEL;
    int* orig    = (int*)(Rb + (size_t)DMODEL * DMODEL);
    int* pos     = orig + M_TOK;
    int* n_agent = pos + M_TOK;

    plan_compact<<<1, 1024, 0, stream>>>(roles, pos, orig, n_agent);
    gather2<<<(M_TOK + DMODEL) / 4, 256, 0, stream>>>(ids, roles, pos, emb, Rm, Xc, Rb, out);
    dim3 grid2(M_TOK / 128, DMODEL / 128);   // (128, 8); early-exit past n_agent
    rse_gemm3<<<grid2, 256, 0, stream>>>(n_agent, orig, Xc, Rb, out);
}